// Round 12
// baseline (890.717 us; speedup 1.0000x reference)
//
#include <hip/hip_runtime.h>
#include <hip/hip_bf16.h>

typedef __bf16 bf16x8 __attribute__((ext_vector_type(8)));
typedef float f32x4 __attribute__((ext_vector_type(4)));
typedef float f32x4v __attribute__((ext_vector_type(4)));
typedef int   i32x4 __attribute__((ext_vector_type(4)));

#define M_DIM 8192
#define K_DIM 4096
#define N_DIM 11008
#define KW 512
#define NG 32
#define NTI 32           // K-tiles of 128 (one quant group each)

#define GLOAD_LDS16(g, l) \
  __builtin_amdgcn_global_load_lds((const __attribute__((address_space(1))) void*)(g), \
                                   (__attribute__((address_space(3))) void*)(l), 16, 0, 0)

// ---------------- prepass 1: x fp32 -> i8 with per-row scale ----------------
__global__ __launch_bounds__(256) void quant_x_i8(
    const float* __restrict__ x, signed char* __restrict__ xq,
    float* __restrict__ sxs)
{
    const int row = blockIdx.x;
    const int t   = threadIdx.x;
    const f32x4v* xr = reinterpret_cast<const f32x4v*>(x + (size_t)row * K_DIM);

    f32x4v v[4];
    float am = 0.f;
    #pragma unroll
    for (int i = 0; i < 4; ++i) {
        v[i] = __builtin_nontemporal_load(xr + t * 4 + i);
        #pragma unroll
        for (int j = 0; j < 4; ++j) am = fmaxf(am, fabsf(v[i][j]));
    }
    #pragma unroll
    for (int off = 32; off; off >>= 1) am = fmaxf(am, __shfl_xor(am, off));
    __shared__ float red[4];
    const int lane = t & 63, w = t >> 6;
    if (lane == 0) red[w] = am;
    __syncthreads();
    am = fmaxf(fmaxf(red[0], red[1]), fmaxf(red[2], red[3]));
    const float inv = am > 1e-30f ? 127.f / am : 0.f;
    if (t == 0) sxs[row] = am > 1e-30f ? am / 127.f : 0.f;

    i32x4 o;
    #pragma unroll
    for (int i = 0; i < 4; ++i) {
        int p = 0;
        #pragma unroll
        for (int j = 0; j < 4; ++j)
            p |= (((int)__builtin_rintf(v[i][j] * inv)) & 255) << (8 * j);
        o[i] = p;
    }
    reinterpret_cast<i32x4*>(xq + (size_t)row * K_DIM)[t] = o;
}

// ---------------- prepass 2: qweight int4 -> i8 (nib - z), exact ----------------
__global__ __launch_bounds__(256) void dequant_w_i8(
    const unsigned int* __restrict__ qw, const int* __restrict__ qz,
    signed char* __restrict__ wq)
{
    size_t idx = (size_t)blockIdx.x * 256 + threadIdx.x;   // one u32 -> 8 i8
    unsigned int q = __builtin_nontemporal_load(qw + idx);
    int row = (int)(idx >> 9);
    int g   = ((int)idx & 511) >> 4;
    int z   = qz[row * NG + g];
    int lo = 0, hi = 0;
    #pragma unroll
    for (int j = 0; j < 4; ++j)
        lo |= ((((int)((q >> (4 * j)) & 15u)) - z) & 255) << (8 * j);
    #pragma unroll
    for (int j = 0; j < 4; ++j)
        hi |= ((((int)((q >> (16 + 4 * j)) & 15u)) - z) & 255) << (8 * j);
    reinterpret_cast<int2*>(wq)[idx] = make_int2(lo, hi);
}

// ---------------- main: 128x128 4-phase i8 GEMM, BK=128 (= one group) ----------------
// Body identical to r11 (76 VGPR, no spill, absmax 0.171875 verified).
// r12 change: SUPERTILE XCD swizzle. r11 evidence: 4 different schedules all land
// at 750-840 us while staging ~5.5 GiB -> ~7 TB/s operand-delivery ceiling
// (LLC-bound; B panels streamed 43 MiB through 4 MiB L2 with no reuse).
// New mapping: XCD x owns bm rows [8x, 8x+8) and walks them in 8bm x 4bn
// supertiles -> 32 concurrent blocks/XCD share 8 A-panels (persistent, 4 MiB)
// + 4 B-panels (rotating, 2 MiB); staging becomes mostly L2-served (34.5 TB/s).

#define STAGE_A(SBUF, SKS, STILE)                                                 \
  do {                                                                            \
    int srow_ = w * 16 + (lane >> 2);                                             \
    GLOAD_LDS16(Aq + (size_t)(m0 + srow_) * K_DIM + (STILE) * 128 + (SKS) * 64 + sslotg * 16, \
                &sA[SBUF][SKS][w * 16][0]);                                       \
  } while (0)

#define STAGE_B(SBUF, SKS, STILE)                                                 \
  do {                                                                            \
    int srow_ = w * 16 + (lane >> 2);                                             \
    GLOAD_LDS16(Bq + (size_t)(n0 + srow_) * K_DIM + (STILE) * 128 + (SKS) * 64 + sslotg * 16, \
                &sB[SBUF][SKS][w * 16][0]);                                       \
  } while (0)

#define PHASE(BUF, KS, SBUF, SKS, STILE, DO_CONV, SCG)                            \
  do {                                                                            \
    i32x4 af_[4];                                                                 \
    i32x4 bcur_[2];                                                               \
    _Pragma("unroll")                                                             \
    for (int m_ = 0; m_ < 4; ++m_) {                                              \
      int row_ = wm * 64 + m_ * 16 + lane16;                                      \
      af_[m_] = *reinterpret_cast<const i32x4*>(&sA[BUF][KS][row_][colByte]);     \
    }                                                                             \
    _Pragma("unroll")                                                             \
    for (int n_ = 0; n_ < 2; ++n_) {                                              \
      int row_ = wn * 32 + n_ * 16 + lane16;                                      \
      bcur_[n_] = *reinterpret_cast<const i32x4*>(&sB[BUF][KS][row_][colByte]);   \
    }                                                                             \
    STAGE_A(SBUF, SKS, STILE);                                                    \
    STAGE_B(SBUF, SKS, STILE);                                                    \
    __builtin_amdgcn_s_barrier();                                                 \
    __builtin_amdgcn_s_setprio(1);                                                \
    _Pragma("unroll")                                                             \
    for (int m_ = 0; m_ < 4; ++m_)                                                \
      _Pragma("unroll")                                                           \
      for (int n_ = 0; n_ < 2; ++n_) {                                            \
        if ((KS) == 0)                                                            \
          acci[m_][n_] = __builtin_amdgcn_mfma_i32_16x16x64_i8(                   \
              af_[m_], bcur_[n_], (i32x4){0, 0, 0, 0}, 0, 0, 0);                  \
        else                                                                      \
          acci[m_][n_] = __builtin_amdgcn_mfma_i32_16x16x64_i8(                   \
              af_[m_], bcur_[n_], acci[m_][n_], 0, 0, 0);                         \
      }                                                                           \
    __builtin_amdgcn_s_setprio(0);                                                \
    if (DO_CONV) {                                                                \
      _Pragma("unroll")                                                           \
      for (int m_ = 0; m_ < 4; ++m_)                                              \
        _Pragma("unroll")                                                         \
        for (int n_ = 0; n_ < 2; ++n_) {                                          \
          float s_ = SCG[n_];                                                     \
          _Pragma("unroll")                                                       \
          for (int r_ = 0; r_ < 4; ++r_)                                          \
            accf[m_][n_][r_] += (float)acci[m_][n_][r_] * s_;                     \
        }                                                                         \
    }                                                                             \
    asm volatile("s_waitcnt vmcnt(4)" ::: "memory");                              \
    __builtin_amdgcn_s_barrier();                                                 \
  } while (0)

__global__ __launch_bounds__(512, 1) void gemm_i8_128(
    const signed char* __restrict__ Aq, const signed char* __restrict__ Bq,
    const float* __restrict__ scales, const float* __restrict__ sxs,
    float* __restrict__ out)
{
    __shared__ __attribute__((aligned(16))) signed char sA[2][2][128][64];  // 32 KiB
    __shared__ __attribute__((aligned(16))) signed char sB[2][2][128][64];  // 32 KiB

    const int t      = threadIdx.x;
    const int lane   = t & 63;
    const int w      = t >> 6;        // wave 0..7
    const int wm     = w >> 2;        // 0..1 -> 64-row M band
    const int wn     = w & 3;         // 0..3 -> 32-col N band
    const int lane16 = lane & 15;
    const int psl    = (lane >> 4) ^ ((lane16 >> 1) & 3);   // read physical 16B slot
    const int colByte = psl * 16;
    const int sslotg = (lane & 3) ^ ((lane >> 3) & 3);      // stage source slot
    const int cl     = lane & 15;

    // Supertile XCD swizzle: XCD x (= bid&7, HW round-robin) owns bm in [8x,8x+8),
    // walked as 8bm x 4bn supertiles (32 blocks = one concurrent XCD wavefront);
    // remainder group of 2 bn at the end. Bijective: 21*32 + 16 = 688 = 8*86.
    int bid = blockIdx.x;
    int xcd = bid & 7;
    int l   = bid >> 3;               // 0..687, ~dispatch order within XCD
    int bm_l, bn;
    if (l < 672) {
        int s = l >> 5;               // supertile 0..20
        int r = l & 31;
        bm_l = r >> 2;                // 0..7
        bn   = s * 4 + (r & 3);
    } else {
        int r = l - 672;              // 0..15
        bm_l = r >> 1;
        bn   = 84 + (r & 1);
    }
    const int m0 = (xcd * 8 + bm_l) * 128;
    const int n0 = bn * 128;

    f32x4 accf[4][2] = {};
    i32x4 acci[4][2];
    float scg0[2], scg1[2];

    // prologue: buf0 <- tile0 (ks0, ks1); buf1 <- tile1 ks0  (6 loads)
    STAGE_A(0, 0, 0); STAGE_B(0, 0, 0);
    STAGE_A(0, 1, 0); STAGE_B(0, 1, 0);
    STAGE_A(1, 0, 1); STAGE_B(1, 0, 1);
    asm volatile("s_waitcnt vmcnt(4)" ::: "memory");
    __builtin_amdgcn_s_barrier();

    for (int it = 0; it < NTI / 2; ++it) {
        const int g0 = it * 2;             // group of buf0's tile
        const int t1 = it * 2 + 1;
        const int t2 = (it * 2 + 2) & (NTI - 1);
        const int t3 = (it * 2 + 3) & (NTI - 1);

        // group scales (g0, g0+1) as float2 per n-frag
        #pragma unroll
        for (int n_ = 0; n_ < 2; ++n_) {
            int coln = n0 + wn * 32 + n_ * 16 + cl;
            float2 sv = *reinterpret_cast<const float2*>(&scales[(size_t)coln * NG + g0]);
            scg0[n_] = sv.x;
            scg1[n_] = sv.y;
        }

        //    compute      | stage          | conv scale
        PHASE(0, 0,          1, 1, t1,        0, scg0);   // P1
        PHASE(0, 1,          0, 0, t2,        1, scg0);   // P2: conv g0
        PHASE(1, 0,          0, 1, t2,        0, scg1);   // P3
        PHASE(1, 1,          1, 0, t3,        1, scg1);   // P4: conv g1
    }

    asm volatile("s_waitcnt vmcnt(0)" ::: "memory");   // drain tail stages

    // epilogue: C/D col=lane&15, row=(lane>>4)*4+r; fold per-row x-scale
    const int rq = lane >> 4;
    #pragma unroll
    for (int m = 0; m < 4; ++m) {
        #pragma unroll
        for (int n = 0; n < 2; ++n) {
            int col = n0 + wn * 32 + n * 16 + cl;
            #pragma unroll
            for (int r = 0; r < 4; ++r) {
                int row = m0 + wm * 64 + m * 16 + rq * 4 + r;
                out[(size_t)row * N_DIM + col] = accf[m][n][r] * sxs[row];
            }
        }
    }
}

// ---------------- fallback: round-1 fused bf16 kernel (128^2) ----------------
#define BM 128
#define BN 128
#define BK 64
#define KSTEPS (K_DIM / BK)

__global__ __launch_bounds__(256) void TurboQuantLinear_gemm_dq(
    const float* __restrict__ x,
    const unsigned int* __restrict__ qw,
    const float* __restrict__ scales,
    const int* __restrict__ qzeros,
    float* __restrict__ out)
{
    __shared__ __bf16 As[BM * BK];
    __shared__ __bf16 Bs[BN * BK];

    const int t    = threadIdx.x;
    const int lane = t & 63;
    const int wave = t >> 6;
    const int wr   = wave >> 1;
    const int wc   = wave & 1;
    const int m0 = blockIdx.x * BM;
    const int n0 = blockIdx.y * BN;

    f32x4 acc[4][4] = {};

    for (int kt = 0; kt < KSTEPS; ++kt) {
        const int k0 = kt * BK;
        const int g  = k0 >> 7;

        #pragma unroll
        for (int i = 0; i < 4; ++i) {
            int o  = t + i * 256;
            int r  = o >> 3;
            int c8 = o & 7;
            const float4* src = reinterpret_cast<const float4*>(
                &x[(size_t)(m0 + r) * K_DIM + k0 + c8 * 8]);
            float4 f0 = src[0];
            float4 f1 = src[1];
            bf16x8 v;
            v[0] = (__bf16)f0.x; v[1] = (__bf16)f0.y; v[2] = (__bf16)f0.z; v[3] = (__bf16)f0.w;
            v[4] = (__bf16)f1.x; v[5] = (__bf16)f1.y; v[6] = (__bf16)f1.z; v[7] = (__bf16)f1.w;
            int slot = c8 ^ (r & 7);
            *reinterpret_cast<bf16x8*>(&As[r * BK + slot * 8]) = v;
        }

        const int kw0 = kt * 8;
        #pragma unroll
        for (int i = 0; i < 4; ++i) {
            int idx = t + i * 256;
            int r   = idx >> 3;
            int wq2 = idx & 7;
            unsigned int q = qw[(size_t)(n0 + r) * KW + kw0 + wq2];
            float s  = scales[(n0 + r) * NG + g];
            float z  = (float)qzeros[(n0 + r) * NG + g];
            float zs = z * s;
            bf16x8 v;
            #pragma unroll
            for (int j = 0; j < 8; ++j) {
                float val = (float)((q >> (4 * j)) & 15u) * s - zs;
                v[j] = (__bf16)val;
            }
            int slot = wq2 ^ (r & 7);
            *reinterpret_cast<bf16x8*>(&Bs[r * BK + slot * 8]) = v;
        }

        __syncthreads();

        const int row_in_l = lane & 15;
        #pragma unroll
        for (int kk = 0; kk < 2; ++kk) {
            const int kslot = kk * 4 + (lane >> 4);
            bf16x8 af[4], bfr[4];
            #pragma unroll
            for (int m = 0; m < 4; ++m) {
                int row = wr * 64 + m * 16 + row_in_l;
                af[m] = *reinterpret_cast<const bf16x8*>(
                    &As[row * BK + ((kslot ^ (row & 7)) * 8)]);
            }
            #pragma unroll
            for (int n = 0; n < 4; ++n) {
                int row = wc * 64 + n * 16 + row_in_l;
                bfr[n] = *reinterpret_cast<const bf16x8*>(
                    &Bs[row * BK + ((kslot ^ (row & 7)) * 8)]);
            }
            #pragma unroll
            for (int m = 0; m < 4; ++m)
                #pragma unroll
                for (int n = 0; n < 4; ++n)
                    acc[m][n] = __builtin_amdgcn_mfma_f32_16x16x32_bf16(
                        af[m], bfr[n], acc[m][n], 0, 0, 0);
        }

        __syncthreads();
    }

    const int cl2 = lane & 15;
    const int rq = lane >> 4;
    #pragma unroll
    for (int m = 0; m < 4; ++m) {
        #pragma unroll
        for (int n = 0; n < 4; ++n) {
            int col = n0 + wc * 64 + n * 16 + cl2;
            #pragma unroll
            for (int r = 0; r < 4; ++r) {
                int row = m0 + wr * 64 + m * 16 + rq * 4 + r;
                out[(size_t)row * N_DIM + col] = acc[m][n][r];
            }
        }
    }
}

extern "C" void kernel_launch(void* const* d_in, const int* in_sizes, int n_in,
                              void* d_out, int out_size, void* d_ws, size_t ws_size,
                              hipStream_t stream) {
    const float*        x      = (const float*)d_in[0];
    const unsigned int* qw     = (const unsigned int*)d_in[1];
    const float*        scales = (const float*)d_in[2];
    const int*          qzeros = (const int*)d_in[3];
    float* out = (float*)d_out;

    const size_t xq_bytes  = (size_t)M_DIM * K_DIM;          // 32 MiB
    const size_t wq_bytes  = (size_t)N_DIM * K_DIM;          // 43 MiB
    const size_t sxs_bytes = (size_t)M_DIM * sizeof(float);  // 32 KiB

    if (ws_size >= xq_bytes + wq_bytes + sxs_bytes) {
        signed char* xq  = (signed char*)d_ws;
        signed char* wqb = (signed char*)d_ws + xq_bytes;
        float*       sxs = (float*)((char*)d_ws + xq_bytes + wq_bytes);

        quant_x_i8<<<dim3(M_DIM), dim3(256), 0, stream>>>(x, xq, sxs);
        dequant_w_i8<<<dim3((N_DIM * KW) / 256), dim3(256), 0, stream>>>(qw, qzeros, wqb);

        // 64 x 86 = 5504 workgroups, supertile-swizzled inside the kernel
        gemm_i8_128<<<dim3(5504), dim3(512), 0, stream>>>(xq, wqb, scales, sxs, out);
    } else {
        dim3 grid(M_DIM / BM, N_DIM / BN);
        TurboQuantLinear_gemm_dq<<<grid, dim3(256), 0, stream>>>(x, qw, scales, qzeros, out);
    }
}

// Round 13
// 756.533 us; speedup vs baseline: 1.1774x; 1.1774x over previous
//
#include <hip/hip_runtime.h>
#include <hip/hip_bf16.h>

typedef __bf16 bf16x8 __attribute__((ext_vector_type(8)));
typedef float f32x4 __attribute__((ext_vector_type(4)));
typedef float f32x4v __attribute__((ext_vector_type(4)));

#define M_DIM 8192
#define K_DIM 4096
#define N_DIM 11008
#define KW 512
#define NG 32
#define NT 64            // K-tiles of 64

#define GLOAD_LDS16(g, l) \
  __builtin_amdgcn_global_load_lds((const __attribute__((address_space(1))) void*)(g), \
                                   (__attribute__((address_space(3))) void*)(l), 16, 0, 0)

// ---------------- merged prepass: x fp32->bf16 (blocks 0..16383) ----------------
// ----------------                 qweight int4->bf16 (blocks 16384..27391) -----
#define XBLOCKS 16384          // 8192*4096/8 octets / 256
#define WBLOCKS 11008          // 11008*512/2 pairs / 256

__global__ __launch_bounds__(256) void prep_bf16(
    const float* __restrict__ x, const unsigned int* __restrict__ qw,
    const float* __restrict__ sc, const int* __restrict__ qz,
    __bf16* __restrict__ xb, __bf16* __restrict__ wb)
{
    const int bid = blockIdx.x;
    const int t   = threadIdx.x;
    if (bid < XBLOCKS) {
        size_t i = (size_t)bid * 256 + t;                 // octet index
        const f32x4v* s = reinterpret_cast<const f32x4v*>(x) + i * 2;
        f32x4v f0 = __builtin_nontemporal_load(s);        // x read exactly once
        f32x4v f1 = __builtin_nontemporal_load(s + 1);
        bf16x8 v;
        v[0] = (__bf16)f0[0]; v[1] = (__bf16)f0[1]; v[2] = (__bf16)f0[2]; v[3] = (__bf16)f0[3];
        v[4] = (__bf16)f1[0]; v[5] = (__bf16)f1[1]; v[6] = (__bf16)f1[2]; v[7] = (__bf16)f1[3];
        *reinterpret_cast<bf16x8*>(xb + i * 8) = v;       // xb cached: GEMM re-reads it
    } else {
        size_t j = (size_t)(bid - XBLOCKS) * 256 + t;     // u32-pair index
        long long q2 = __builtin_nontemporal_load(
            reinterpret_cast<const long long*>(qw) + j);  // read exactly once
        unsigned int lo = (unsigned int)q2;
        unsigned int hi = (unsigned int)((unsigned long long)q2 >> 32);
        size_t idx = j * 2;                               // first u32 index
        int row = (int)(idx >> 9);
        int g   = ((int)idx & 511) >> 4;                  // pair never crosses a group
        float s  = sc[row * NG + g];
        float zs = (float)qz[row * NG + g] * s;
        bf16x8 v0, v1;
        #pragma unroll
        for (int k = 0; k < 8; ++k)
            v0[k] = (__bf16)((float)((lo >> (4 * k)) & 15u) * s - zs);
        #pragma unroll
        for (int k = 0; k < 8; ++k)
            v1[k] = (__bf16)((float)((hi >> (4 * k)) & 15u) * s - zs);
        *reinterpret_cast<bf16x8*>(wb + idx * 8)     = v0;
        *reinterpret_cast<bf16x8*>(wb + idx * 8 + 8) = v1;
    }
}

// ---------------- main: 256x256 8-phase bf16 GEMM (r5/r6 best, verified) -------
// lds[buf][op(0=A,1=B)][ks][row 0..255][col 0..31 bf16]; 128 KiB total.
// swizzle: physical 16B-slot = logical_slot ^ ((row>>1)&3)
// Stage-slot order gives every sub-tile a 6-7 phase lead; completion gates
// only at P4/P8 with vmcnt(6) (m218 discipline).

#define STAGE_SUB(SBUF, SOP, SKS, STILE)                                          \
  do {                                                                            \
    _Pragma("unroll")                                                             \
    for (int j_ = 0; j_ < 2; ++j_) {                                              \
      int srow_ = j_ * 128 + w * 16 + (lane >> 2);                                \
      const __bf16* sp_ = ((SOP) == 0)                                            \
        ? Ag + (size_t)(m0 + srow_) * K_DIM + (STILE) * 64 + (SKS) * 32 + sslotg * 8 \
        : Bg + (size_t)(n0 + srow_) * K_DIM + (STILE) * 64 + (SKS) * 32 + sslotg * 8; \
      GLOAD_LDS16(sp_, &lds[SBUF][SOP][SKS][j_ * 128 + w * 16][0]);               \
    }                                                                             \
  } while (0)

#define PHASE(BUF, MH, KS, LOADB, SBUF, SOP, SKS, STILE, DO_VM)                   \
  do {                                                                            \
    bf16x8 af_[4];                                                                \
    _Pragma("unroll")                                                             \
    for (int m_ = 0; m_ < 4; ++m_) {                                              \
      int row_ = wm * 128 + (MH) * 64 + m_ * 16 + lane16;                         \
      af_[m_] = *reinterpret_cast<const bf16x8*>(&lds[BUF][0][KS][row_][colElem]);\
    }                                                                             \
    if (LOADB) {                                                                  \
      _Pragma("unroll")                                                           \
      for (int n_ = 0; n_ < 4; ++n_) {                                            \
        int row_ = wn * 64 + n_ * 16 + lane16;                                    \
        bcur[n_] = *reinterpret_cast<const bf16x8*>(&lds[BUF][1][KS][row_][colElem]);\
      }                                                                           \
    }                                                                             \
    STAGE_SUB(SBUF, SOP, SKS, STILE);                                             \
    __builtin_amdgcn_s_barrier();                                                 \
    __builtin_amdgcn_s_setprio(1);                                                \
    _Pragma("unroll")                                                             \
    for (int m_ = 0; m_ < 4; ++m_)                                                \
      _Pragma("unroll")                                                           \
      for (int n_ = 0; n_ < 4; ++n_)                                              \
        acc[(MH) * 4 + m_][n_] = __builtin_amdgcn_mfma_f32_16x16x32_bf16(         \
            af_[m_], bcur[n_], acc[(MH) * 4 + m_][n_], 0, 0, 0);                  \
    __builtin_amdgcn_s_setprio(0);                                                \
    if (DO_VM) asm volatile("s_waitcnt vmcnt(6)" ::: "memory");                   \
    __builtin_amdgcn_s_barrier();                                                 \
  } while (0)

__global__ __launch_bounds__(512, 2) void gemm_bf16_8phase(
    const __bf16* __restrict__ Ag, const __bf16* __restrict__ Bg,
    float* __restrict__ out)
{
    __shared__ __attribute__((aligned(16))) __bf16 lds[2][2][2][256][32];

    const int t      = threadIdx.x;
    const int lane   = t & 63;
    const int w      = t >> 6;
    const int wm     = w >> 2;
    const int wn     = w & 3;
    const int lane16 = lane & 15;
    const int psl    = (lane >> 4) ^ ((lane16 >> 1) & 3);
    const int colElem = psl * 8;
    const int sslotg = (lane & 3) ^ ((lane >> 3) & 3);

    int bid = blockIdx.x;
    int wg  = (bid & 7) * 172 + (bid >> 3);   // 1376 = 8*172, bijective
    int bm  = wg / 43;
    int bn  = wg - bm * 43;
    const int m0 = bm * 256;
    const int n0 = bn * 256;

    f32x4 acc[8][4] = {};
    bf16x8 bcur[4];

    // prologue: 7 sub-tiles (14 loads); wait only for buf0 (oldest 8) before P1
    STAGE_SUB(0, 0, 0, 0);
    STAGE_SUB(0, 1, 0, 0);
    STAGE_SUB(0, 0, 1, 0);
    STAGE_SUB(0, 1, 1, 0);
    STAGE_SUB(1, 0, 0, 1);
    STAGE_SUB(1, 1, 0, 1);
    STAGE_SUB(1, 1, 1, 1);
    asm volatile("s_waitcnt vmcnt(6)" ::: "memory");
    __builtin_amdgcn_s_barrier();

    for (int it = 0; it < NT / 2; ++it) {
        const int t1 = (it * 2 + 1) & (NT - 1);
        const int t2 = (it * 2 + 2) & (NT - 1);
        const int t3 = (it * 2 + 3) & (NT - 1);

        //    read-buf mh ks loadB | stage-buf op ks tile | vmcnt(6)?
        PHASE(0,       0, 0, 1,      1,       0, 1, t1,     0);   // P1
        PHASE(0,       1, 0, 0,      0,       1, 0, t2,     0);   // P2
        PHASE(0,       0, 1, 1,      0,       0, 0, t2,     0);   // P3
        PHASE(0,       1, 1, 0,      0,       1, 1, t2,     1);   // P4
        PHASE(1,       0, 0, 1,      0,       0, 1, t2,     0);   // P5
        PHASE(1,       1, 0, 0,      1,       1, 0, t3,     0);   // P6
        PHASE(1,       0, 1, 1,      1,       0, 0, t3,     0);   // P7
        PHASE(1,       1, 1, 0,      1,       1, 1, t3,     1);   // P8
    }

    asm volatile("s_waitcnt vmcnt(0)" ::: "memory");   // drain tail garbage stages

    // epilogue: plain cached stores
    const int cl = lane & 15;
    const int rq = lane >> 4;
    #pragma unroll
    for (int mi = 0; mi < 8; ++mi) {
        #pragma unroll
        for (int n = 0; n < 4; ++n) {
            int col = n0 + wn * 64 + n * 16 + cl;
            #pragma unroll
            for (int r = 0; r < 4; ++r) {
                int row = m0 + wm * 128 + (mi >> 2) * 64 + (mi & 3) * 16 + rq * 4 + r;
                out[(size_t)row * N_DIM + col] = acc[mi][n][r];
            }
        }
    }
}

// ---------------- fallback: round-1 fused bf16 kernel (128^2) ----------------
#define BM 128
#define BN 128
#define BK 64
#define KSTEPS (K_DIM / BK)

__global__ __launch_bounds__(256) void TurboQuantLinear_gemm_dq(
    const float* __restrict__ x,
    const unsigned int* __restrict__ qw,
    const float* __restrict__ scales,
    const int* __restrict__ qzeros,
    float* __restrict__ out)
{
    __shared__ __bf16 As[BM * BK];
    __shared__ __bf16 Bs[BN * BK];

    const int t    = threadIdx.x;
    const int lane = t & 63;
    const int wave = t >> 6;
    const int wr   = wave >> 1;
    const int wc   = wave & 1;
    const int m0 = blockIdx.x * BM;
    const int n0 = blockIdx.y * BN;

    f32x4 acc[4][4] = {};

    for (int kt = 0; kt < KSTEPS; ++kt) {
        const int k0 = kt * BK;
        const int g  = k0 >> 7;

        #pragma unroll
        for (int i = 0; i < 4; ++i) {
            int o  = t + i * 256;
            int r  = o >> 3;
            int c8 = o & 7;
            const float4* src = reinterpret_cast<const float4*>(
                &x[(size_t)(m0 + r) * K_DIM + k0 + c8 * 8]);
            float4 f0 = src[0];
            float4 f1 = src[1];
            bf16x8 v;
            v[0] = (__bf16)f0.x; v[1] = (__bf16)f0.y; v[2] = (__bf16)f0.z; v[3] = (__bf16)f0.w;
            v[4] = (__bf16)f1.x; v[5] = (__bf16)f1.y; v[6] = (__bf16)f1.z; v[7] = (__bf16)f1.w;
            int slot = c8 ^ (r & 7);
            *reinterpret_cast<bf16x8*>(&As[r * BK + slot * 8]) = v;
        }

        const int kw0 = kt * 8;
        #pragma unroll
        for (int i = 0; i < 4; ++i) {
            int idx = t + i * 256;
            int r   = idx >> 3;
            int wq2 = idx & 7;
            unsigned int q = qw[(size_t)(n0 + r) * KW + kw0 + wq2];
            float s  = scales[(n0 + r) * NG + g];
            float z  = (float)qzeros[(n0 + r) * NG + g];
            float zs = z * s;
            bf16x8 v;
            #pragma unroll
            for (int j = 0; j < 8; ++j) {
                float val = (float)((q >> (4 * j)) & 15u) * s - zs;
                v[j] = (__bf16)val;
            }
            int slot = wq2 ^ (r & 7);
            *reinterpret_cast<bf16x8*>(&Bs[r * BK + slot * 8]) = v;
        }

        __syncthreads();

        const int row_in_l = lane & 15;
        #pragma unroll
        for (int kk = 0; kk < 2; ++kk) {
            const int kslot = kk * 4 + (lane >> 4);
            bf16x8 af[4], bfr[4];
            #pragma unroll
            for (int m = 0; m < 4; ++m) {
                int row = wr * 64 + m * 16 + row_in_l;
                af[m] = *reinterpret_cast<const bf16x8*>(
                    &As[row * BK + ((kslot ^ (row & 7)) * 8)]);
            }
            #pragma unroll
            for (int n = 0; n < 4; ++n) {
                int row = wc * 64 + n * 16 + row_in_l;
                bfr[n] = *reinterpret_cast<const bf16x8*>(
                    &Bs[row * BK + ((kslot ^ (row & 7)) * 8)]);
            }
            #pragma unroll
            for (int m = 0; m < 4; ++m)
                #pragma unroll
                for (int n = 0; n < 4; ++n)
                    acc[m][n] = __builtin_amdgcn_mfma_f32_16x16x32_bf16(
                        af[m], bfr[n], acc[m][n], 0, 0, 0);
        }

        __syncthreads();
    }

    const int cl2 = lane & 15;
    const int rq = lane >> 4;
    #pragma unroll
    for (int m = 0; m < 4; ++m) {
        #pragma unroll
        for (int n = 0; n < 4; ++n) {
            int col = n0 + wc * 64 + n * 16 + cl2;
            #pragma unroll
            for (int r = 0; r < 4; ++r) {
                int row = m0 + wr * 64 + m * 16 + rq * 4 + r;
                out[(size_t)row * N_DIM + col] = acc[m][n][r];
            }
        }
    }
}

extern "C" void kernel_launch(void* const* d_in, const int* in_sizes, int n_in,
                              void* d_out, int out_size, void* d_ws, size_t ws_size,
                              hipStream_t stream) {
    const float*        x      = (const float*)d_in[0];
    const unsigned int* qw     = (const unsigned int*)d_in[1];
    const float*        scales = (const float*)d_in[2];
    const int*          qzeros = (const int*)d_in[3];
    float* out = (float*)d_out;

    const size_t xb_bytes = (size_t)M_DIM * K_DIM * sizeof(__bf16);  // 64 MiB
    const size_t wb_bytes = (size_t)N_DIM * K_DIM * sizeof(__bf16);  // 86 MiB

    if (ws_size >= xb_bytes + wb_bytes) {
        __bf16* xb = (__bf16*)d_ws;
        __bf16* wb = (__bf16*)((char*)d_ws + xb_bytes);

        prep_bf16<<<dim3(XBLOCKS + WBLOCKS), dim3(256), 0, stream>>>(
            x, qw, scales, qzeros, xb, wb);

        gemm_bf16_8phase<<<dim3(1376), dim3(512), 0, stream>>>(xb, wb, out);
    } else {
        dim3 grid(M_DIM / BM, N_DIM / BN);
        TurboQuantLinear_gemm_dq<<<grid, dim3(256), 0, stream>>>(x, qw, scales, qzeros, out);
    }
}